// Round 12
// baseline (283.599 us; speedup 1.0000x reference)
//
#include <hip/hip_runtime.h>

#define TQ 2048
#define NB 2
#define NH 32
#define NKV 8
#define HD 64
#define DIN 2048
#define DOUT 2048
#define NQKV 3072   // GEMM N: 2048 q | 512 k | 512 v
#define QK_W 2560   // QKV buffer row width (q|k only; v split out)
#define GK 2048     // K dim of both GEMMs

typedef unsigned short u16;
typedef unsigned int u32;
typedef __attribute__((ext_vector_type(8))) short bf16x8;
typedef __attribute__((ext_vector_type(4))) float f32x4;
typedef __attribute__((ext_vector_type(4))) u16 u16x4;

typedef __attribute__((address_space(1))) const u32 gas_u32;
typedef __attribute__((address_space(3))) u32 las_u32;

#define NEG (-1.0e30f)
#define CL2 0.18033688f   // 0.125 * log2(e)

__device__ __forceinline__ u16 f2bf(float f) {
  u32 u = __float_as_uint(f);
  u += 0x7fffu + ((u >> 16) & 1u);
  return (u16)(u >> 16);
}
__device__ __forceinline__ float bf2f(u16 h) { return __uint_as_float(((u32)h) << 16); }
__device__ __forceinline__ u32 cvtpk(float lo, float hi) {
  u32 r;
  asm("v_cvt_pk_bf16_f32 %0, %1, %2" : "=v"(r) : "v"(lo), "v"(hi));
  return r;
}
// native exp2; s_nop covers the TRANS->consumer wait state the compiler
// cannot insert around opaque inline asm.
__device__ __forceinline__ float exp2g(float x) {
  float r;
  asm("v_exp_f32 %0, %1\n\ts_nop 0" : "=v"(r) : "v"(x));
  return r;
}

// =============== fused prep: cvt | 4x transpose | rope table ===============
__device__ __forceinline__ void prep_transpose(const float* __restrict__ src, int nsrc,
                                               u16* __restrict__ dst, int row0, int vb,
                                               float (*tile)[33]) {
  const int nTK = GK / 32;
  int kt = vb % nTK, nt = vb / nTK;
  int k0 = kt * 32, n0 = nt * 32;
  int rr = threadIdx.x >> 5, cc = threadIdx.x & 31;
#pragma unroll
  for (int p = 0; p < 4; ++p) {
    int kl = p * 8 + rr;
    tile[kl][cc] = src[(size_t)(k0 + kl) * nsrc + n0 + cc];
  }
  __syncthreads();
#pragma unroll
  for (int p = 0; p < 4; ++p) {
    int nl = p * 8 + rr;
    dst[(size_t)(row0 + n0 + nl) * GK + k0 + cc] = f2bf(tile[cc][nl]);
  }
}

__global__ __launch_bounds__(256)
void k_prep(const float* __restrict__ x,  const float* __restrict__ Wq,
            const float* __restrict__ Wk, const float* __restrict__ Wv,
            const float* __restrict__ Wo, u16* __restrict__ xb,
            u16* __restrict__ WqkvT, u16* __restrict__ WoT,
            float2* __restrict__ tab) {
  __shared__ float tile[32][33];
  const int bid = blockIdx.x;
  if (bid < 8192) {                       // fp32 -> bf16 convert, 4 elems/thread
    int i = bid * 256 + threadIdx.x;
    f32x4 v = *(const f32x4*)(x + (size_t)i * 4);
    u16x4 o;
    o[0] = f2bf(v[0]); o[1] = f2bf(v[1]); o[2] = f2bf(v[2]); o[3] = f2bf(v[3]);
    *(u16x4*)(xb + (size_t)i * 4) = o;
  } else if (bid < 12288) {
    prep_transpose(Wq, 2048, WqkvT, 0,    bid - 8192,  tile);
  } else if (bid < 13312) {
    prep_transpose(Wk, 512,  WqkvT, 2048, bid - 12288, tile);
  } else if (bid < 14336) {
    prep_transpose(Wv, 512,  WqkvT, 2560, bid - 13312, tile);
  } else if (bid < 18432) {
    prep_transpose(Wo, 2048, WoT,   0,    bid - 14336, tile);
  } else {                                // rope cos/sin table
    int idx = (bid - 18432) * 256 + threadIdx.x;
    int t = idx >> 5, i = idx & 31;
    float inv = 1.0f / powf(10000.0f, (float)i / 32.0f);
    float ang = (float)t * inv;
    tab[idx] = make_float2(cosf(ang), sinf(ang));
  }
}

// ---------------- bf16 GEMM: C[M][N] = A[M][GK] * Bt[N][GK]^T ----------------
// 128x128 tile, BK=64, 4 waves (2x2), global_load_lds double-buffer,
// T2 XOR swizzle applied via pre-swizzled global source (linear LDS dest).
// MODE 0: bf16 out; q|k cols (<2560) get fused RoPE then -> QKV (stride 2560);
//         v cols (>=2560) -> transposed Vt ([b][kvh][d][t]).
// MODE 1: f32 out, stride N.
template <int MODE>
__global__ __launch_bounds__(256, 2)
void k_gemm(const u16* __restrict__ A, const u16* __restrict__ Bt,
            u16* __restrict__ QKV, u16* __restrict__ Vt, float* __restrict__ Cf,
            const float2* __restrict__ tab, int N) {
  __shared__ __align__(16) u16 lds[2][16384];   // per buf: A 128x64 | B 128x64
  const int tid = threadIdx.x;
  const int lane = tid & 63, wid = tid >> 6;
  const int nTN = N >> 7;
  const int tm = blockIdx.x / nTN, tn = blockIdx.x % nTN;
  const int m0 = tm << 7, n0 = tn << 7;
  const int l15 = lane & 15, lg = lane >> 4;
  const int wr = (wid >> 1) << 6, wc = (wid & 1) << 6;

  f32x4 acc[4][4] = {};

  auto stage = [&](int buf, int k0) {
    u16* base = &lds[buf][0];
#pragma unroll
    for (int p = 0; p < 4; ++p) {
      int c = p * 256 + tid;
      int row = c >> 3, kb = c & 7;
      int ksrc = k0 + ((kb ^ (row & 7)) << 3);   // inverse-swizzled source col
      const u16* sA = A + (size_t)(m0 + row) * GK + ksrc;
      __builtin_amdgcn_global_load_lds((gas_u32*)sA, (las_u32*)(base + c * 8), 16, 0, 0);
      const u16* sB = Bt + (size_t)(n0 + row) * GK + ksrc;
      __builtin_amdgcn_global_load_lds((gas_u32*)sB, (las_u32*)(base + 8192 + c * 8), 16, 0, 0);
    }
  };

  auto compute = [&](int buf) {
    const u16* ldsA = &lds[buf][0];
    const u16* ldsB = &lds[buf][8192];
#pragma unroll
    for (int kk = 0; kk < 2; ++kk) {
      bf16x8 af[4], bfr[4];
#pragma unroll
      for (int m = 0; m < 4; ++m) {
        int row = wr + m * 16 + l15;
        int koff = (kk * 32 + lg * 8) ^ ((row & 7) << 3);
        af[m] = *(const bf16x8*)(ldsA + row * 64 + koff);
      }
#pragma unroll
      for (int n = 0; n < 4; ++n) {
        int row = wc + n * 16 + l15;
        int koff = (kk * 32 + lg * 8) ^ ((row & 7) << 3);
        bfr[n] = *(const bf16x8*)(ldsB + row * 64 + koff);
      }
#pragma unroll
      for (int m = 0; m < 4; ++m)
#pragma unroll
        for (int n = 0; n < 4; ++n)
          acc[m][n] = __builtin_amdgcn_mfma_f32_16x16x32_bf16(af[m], bfr[n], acc[m][n], 0, 0, 0);
    }
  };

  stage(0, 0);
  __syncthreads();
  const int nk = GK / 64;
  for (int t = 0; t < nk; ++t) {
    if (t + 1 < nk) stage((t + 1) & 1, (t + 1) * 64);
    compute(t & 1);
    __syncthreads();
  }

  if (MODE == 1) {
#pragma unroll
    for (int m = 0; m < 4; ++m)
#pragma unroll
      for (int n = 0; n < 4; ++n)
#pragma unroll
        for (int r = 0; r < 4; ++r) {
          int row = m0 + wr + m * 16 + lg * 4 + r;
          int col = n0 + wc + n * 16 + l15;
          Cf[(size_t)row * N + col] = acc[m][n][r];
        }
  } else if (n0 >= 2560) {   // V tile -> transposed Vt[b][kvh][d][t]
#pragma unroll
    for (int m = 0; m < 4; ++m)
#pragma unroll
      for (int n = 0; n < 4; ++n)
#pragma unroll
        for (int r = 0; r < 4; ++r) {
          int row = m0 + wr + m * 16 + lg * 4 + r;
          int col = n0 + wc + n * 16 + l15;
          int dh = col - 2560, kvh = dh >> 6, d = dh & 63;
          int bb = row >> 11, tt = row & 2047;
          Vt[(((size_t)bb * NKV + kvh) * 64 + d) * TQ + tt] = f2bf(acc[m][n][r]);
        }
  } else {                   // q|k tile: fused RoPE (pair partner via shfl_xor 1)
#pragma unroll
    for (int m = 0; m < 4; ++m)
#pragma unroll
      for (int n = 0; n < 4; ++n) {
        int col = n0 + wc + n * 16 + l15;
        int dh = (col & 63) >> 1;
        float sgn = (col & 1) ? 1.0f : -1.0f;
#pragma unroll
        for (int r = 0; r < 4; ++r) {
          int row = m0 + wr + m * 16 + lg * 4 + r;
          float a = acc[m][n][r];
          float b = __shfl_xor(a, 1);
          int t = row & (TQ - 1);
          float2 csv = tab[t * 32 + dh];
          float o = a * csv.x + sgn * b * csv.y;
          QKV[(size_t)row * QK_W + col] = f2bf(o);
        }
      }
  }
}

// ---------------- causal GQA flash attention, head-group fused ----------------
// block = (b, kvh, q-tile of 64). 4 waves x 16 q rows. KVBLK=64.
// All 4 heads of the KV group processed SEQUENTIALLY per KV tile (no barrier
// between heads): K/V staging, barriers, and KV HBM traffic amortized 4x vs the
// per-head version, and the 4 independent head-chains give within-wave ILP
// (exp-VALU of head h overlaps in-flight MFMA of neighboring heads).
// Layouts identical to the proven r4 kernel with m -> head loop swap (m=1).
// P uses per-wave ping-pong buffers (head parity) -> no same-wave WAR fence.
__global__ __launch_bounds__(256, 3)
void k_attn(const u16* __restrict__ QKV, const u16* __restrict__ Vt, u16* __restrict__ ctx) {
  __shared__ __align__(16) u16 Ksh[2][4096];   // [kv 64][d 64] col-swizzled
  __shared__ __align__(16) u16 Vsh[2][4096];   // [d 64][t 64] col-swizzled
  __shared__ __align__(16) u16 Psh[4][2][1024];// per-wave ping-pong [16 q][64 kv]
  const int tid = threadIdx.x, lane = tid & 63, w = tid >> 6;
  const int l15 = lane & 15, lg = lane >> 4;
  const int bid = blockIdx.x;
  const int qt = 31 - (bid >> 4);              // heavy-first, q-tile of 64
  const int rem = bid & 15;
  const int kvh = rem & 7, b = rem >> 3;
  const int q0 = qt << 6;
  const int qb = q0 + w * 16;                  // this wave's q rows: qb + l15
  const size_t rowbase = (size_t)b * TQ;
  const u16* Vg = Vt + ((size_t)(b * NKV + kvh)) * 64 * TQ;

  auto stage = [&](int buf, int kv0) {
    u16* kd = &Ksh[buf][0];
    u16* vd = &Vsh[buf][0];
#pragma unroll
    for (int p = 0; p < 2; ++p) {
      int c = p * 256 + tid;
      int row = c >> 3, kb = c & 7;
      int off = (kb ^ (row & 7)) << 3;
      const u16* sK = QKV + (rowbase + kv0 + row) * QK_W + 2048 + kvh * 64 + off;
      __builtin_amdgcn_global_load_lds((gas_u32*)sK, (las_u32*)(kd + c * 8), 16, 0, 0);
      const u16* sV = Vg + (size_t)row * TQ + kv0 + off;
      __builtin_amdgcn_global_load_lds((gas_u32*)sV, (las_u32*)(vd + c * 8), 16, 0, 0);
    }
  };

  // Q fragments for all 4 heads of the group (B-operand: col q=l15, k=d chunk)
  bf16x8 qf[4][2];
#pragma unroll
  for (int hp = 0; hp < 4; ++hp)
#pragma unroll
    for (int kk = 0; kk < 2; ++kk)
      qf[hp][kk] = *(const bf16x8*)(QKV + (rowbase + qb + l15) * QK_W +
                                    (kvh * 4 + hp) * 64 + kk * 32 + lg * 8);

  float m_run[4] = {NEG, NEG, NEG, NEG}, l_run[4] = {0.f, 0.f, 0.f, 0.f};
  f32x4 oacc[4][4] = {};

  stage(0, 0);
  const int nt = qt + 1;
  for (int t = 0; t < nt; ++t) {
    const int kv0 = t << 6;
    __syncthreads();                  // drains vmcnt(0): buf[t&1] ready block-wide
    if (t + 1 < nt) stage((t + 1) & 1, kv0 + 64);

    const u16* Kl = &Ksh[t & 1][0];
    const u16* Vl = &Vsh[t & 1][0];
    const bool maskT = (kv0 + 63 > qb);
    const int swz = (l15 & 7) << 3;

#pragma unroll
    for (int hp = 0; hp < 4; ++hp) {
      // S^T = K * Q_h (raw): lane owns col q = qb+l15, row kv = kv0+c*16+lg*4+r
      f32x4 stv[4];
#pragma unroll
      for (int c = 0; c < 4; ++c) {
        const int krow = c * 16 + l15;
        const int ks = (krow & 7) << 3;
        f32x4 z = {};
#pragma unroll
        for (int kk = 0; kk < 2; ++kk) {
          bf16x8 kf = *(const bf16x8*)(Kl + krow * 64 + ((kk * 32 + lg * 8) ^ ks));
          z = __builtin_amdgcn_mfma_f32_16x16x32_bf16(kf, qf[hp][kk], z, 0, 0, 0);
        }
        stv[c] = z;
      }

      // causal mask (diagonal tile only, wave-uniform) + row max (raw units)
      float mx = NEG;
      if (maskT) {
        const int qpos = qb + l15;
#pragma unroll
        for (int c = 0; c < 4; ++c)
#pragma unroll
          for (int r = 0; r < 4; ++r) {
            int kvpos = kv0 + c * 16 + lg * 4 + r;
            float sv = stv[c][r];
            sv = (kvpos > qpos) ? NEG : sv;
            stv[c][r] = sv;
            mx = fmaxf(mx, sv);
          }
      } else {
#pragma unroll
        for (int c = 0; c < 4; ++c)
#pragma unroll
          for (int r = 0; r < 4; ++r) mx = fmaxf(mx, stv[c][r]);
      }
      mx = fmaxf(mx, __shfl_xor(mx, 16));
      mx = fmaxf(mx, __shfl_xor(mx, 32));

      // defer-max: rescale only when some row grew past raw-threshold 64 (= e^8)
      if (__any(mx > m_run[hp] + 64.0f)) {
        float nm = fmaxf(m_run[hp], mx);
        float sc = exp2g((m_run[hp] - nm) * CL2);
        m_run[hp] = nm;
        l_run[hp] *= sc;
#pragma unroll
        for (int dt = 0; dt < 4; ++dt) oacc[hp][dt] *= sc;
      }

      // P = exp2(S*CL2 - m*CL2) -> bf16, per-wave ping-pong LDS [16 q][64 kv]
      u16* Pw = &Psh[w][hp & 1][0];
      {
        const float msc = m_run[hp] * CL2;
        float ssum = 0.f;
#pragma unroll
        for (int c = 0; c < 4; ++c) {
          float p0 = exp2g(stv[c][0] * CL2 - msc);
          float p1 = exp2g(stv[c][1] * CL2 - msc);
          float p2 = exp2g(stv[c][2] * CL2 - msc);
          float p3 = exp2g(stv[c][3] * CL2 - msc);
          ssum += (p0 + p1) + (p2 + p3);
          const int kvb = (c * 16 + lg * 4) ^ swz;
          *(u32*)(Pw + l15 * 64 + kvb)       = cvtpk(p0, p1);
          *(u32*)(Pw + l15 * 64 + (kvb | 2)) = cvtpk(p2, p3);
        }
        ssum += __shfl_xor(ssum, 16);
        ssum += __shfl_xor(ssum, 32);
        l_run[hp] += ssum;
      }

      // O^T += V^T * P : lane owns O^T[d = dt*16+lg*4+r][q = l15]
      bf16x8 pf[2];
#pragma unroll
      for (int kc = 0; kc < 2; ++kc)
        pf[kc] = *(const bf16x8*)(Pw + l15 * 64 + ((kc * 32 + lg * 8) ^ swz));
#pragma unroll
      for (int dt = 0; dt < 4; ++dt) {
        const int vrow = dt * 16 + l15;
        const int vs = (vrow & 7) << 3;
#pragma unroll
        for (int kc = 0; kc < 2; ++kc) {
          bf16x8 vf = *(const bf16x8*)(Vl + vrow * 64 + ((kc * 32 + lg * 8) ^ vs));
          oacc[hp][dt] = __builtin_amdgcn_mfma_f32_16x16x32_bf16(vf, pf[kc], oacc[hp][dt], 0, 0, 0);
        }
      }
    }
  }

  // epilogue: normalize, write ctx[q][h*64+d] as u32 pairs
#pragma unroll
  for (int hp = 0; hp < 4; ++hp) {
    float inv = 1.0f / l_run[hp];
    size_t row = rowbase + qb + l15;
    int hcol = (kvh * 4 + hp) * 64;
#pragma unroll
    for (int dt = 0; dt < 4; ++dt) {
      int col = hcol + dt * 16 + lg * 4;
      u32 w0 = cvtpk(oacc[hp][dt][0] * inv, oacc[hp][dt][1] * inv);
      u32 w1 = cvtpk(oacc[hp][dt][2] * inv, oacc[hp][dt][3] * inv);
      *(u32*)(ctx + row * DOUT + col) = w0;
      *(u32*)(ctx + row * DOUT + col + 2) = w1;
    }
  }
}

// ---------------- host launcher ----------------
extern "C" void kernel_launch(void* const* d_in, const int* in_sizes, int n_in,
                              void* d_out, int out_size, void* d_ws, size_t ws_size,
                              hipStream_t stream) {
  const float* x  = (const float*)d_in[0];
  const float* Wq = (const float*)d_in[1];
  const float* Wk = (const float*)d_in[2];
  const float* Wv = (const float*)d_in[3];
  const float* Wo = (const float*)d_in[4];
  float* out = (float*)d_out;

  char* ws = (char*)d_ws;
  size_t off = 0;
  auto alloc = [&](size_t bytes) -> void* {
    void* p = ws + off;
    off += (bytes + 255) & ~(size_t)255;
    return p;
  };
  const int rows = NB * TQ;  // 4096
  u16*    xb    = (u16*)alloc((size_t)rows * DIN * 2);
  u16*    WqkvT = (u16*)alloc((size_t)NQKV * GK * 2);
  u16*    WoT   = (u16*)alloc((size_t)DOUT * GK * 2);
  u16*    QKV   = (u16*)alloc((size_t)rows * QK_W * 2);
  u16*    Vt    = (u16*)alloc((size_t)NB * NKV * 64 * TQ * 2);
  u16*    ctx   = (u16*)alloc((size_t)rows * DOUT * 2);
  float2* tab   = (float2*)alloc((size_t)TQ * 32 * sizeof(float2));

  k_prep<<<dim3(18688), dim3(256), 0, stream>>>(x, Wq, Wk, Wv, Wo, xb, WqkvT, WoT, tab);
  k_gemm<0><<<dim3((rows / 128) * (NQKV / 128)), dim3(256), 0, stream>>>(xb, WqkvT, QKV, Vt, nullptr, tab, NQKV);
  k_attn<<<dim3(NB * NKV * (TQ / 64)), dim3(256), 0, stream>>>(QKV, Vt, ctx);
  k_gemm<1><<<dim3((rows / 128) * (DOUT / 128)), dim3(256), 0, stream>>>(ctx, WoT, nullptr, nullptr, out, nullptr, DOUT);
}

// Round 13
// 184.392 us; speedup vs baseline: 1.5380x; 1.5380x over previous
//
#include <hip/hip_runtime.h>

#define TQ 2048
#define NB 2
#define NH 32
#define NKV 8
#define HD 64
#define DIN 2048
#define DOUT 2048
#define NQKV 3072   // GEMM N: 2048 q | 512 k | 512 v
#define QK_W 2560   // QKV buffer row width (q|k only; v split out)
#define GK 2048     // K dim of both GEMMs

typedef unsigned short u16;
typedef unsigned int u32;
typedef __attribute__((ext_vector_type(8))) short bf16x8;
typedef __attribute__((ext_vector_type(4))) float f32x4;
typedef __attribute__((ext_vector_type(4))) u16 u16x4;

typedef __attribute__((address_space(1))) const u32 gas_u32;
typedef __attribute__((address_space(3))) u32 las_u32;

#define NEG (-1.0e30f)
#define CL2 0.18033688f   // 0.125 * log2(e)

__device__ __forceinline__ u16 f2bf(float f) {
  u32 u = __float_as_uint(f);
  u += 0x7fffu + ((u >> 16) & 1u);
  return (u16)(u >> 16);
}
__device__ __forceinline__ float bf2f(u16 h) { return __uint_as_float(((u32)h) << 16); }
__device__ __forceinline__ u32 cvtpk(float lo, float hi) {
  u32 r;
  asm("v_cvt_pk_bf16_f32 %0, %1, %2" : "=v"(r) : "v"(lo), "v"(hi));
  return r;
}
// native exp2; s_nop covers the TRANS->consumer wait state the compiler
// cannot insert around opaque inline asm.
__device__ __forceinline__ float exp2g(float x) {
  float r;
  asm("v_exp_f32 %0, %1\n\ts_nop 0" : "=v"(r) : "v"(x));
  return r;
}

// =============== fused prep: cvt | 4x transpose | rope table ===============
// All six prep tasks are mutually independent; one launch lets them overlap
// across CUs instead of serializing as separate graph nodes.
// Block ranges: [0,8192) cvt; [8192,12288) Wq^T; [12288,13312) Wk^T;
// [13312,14336) Wv^T; [14336,18432) Wo^T; [18432,18688) rope table.
__device__ __forceinline__ void prep_transpose(const float* __restrict__ src, int nsrc,
                                               u16* __restrict__ dst, int row0, int vb,
                                               float (*tile)[33]) {
  const int nTK = GK / 32;
  int kt = vb % nTK, nt = vb / nTK;
  int k0 = kt * 32, n0 = nt * 32;
  int rr = threadIdx.x >> 5, cc = threadIdx.x & 31;
#pragma unroll
  for (int p = 0; p < 4; ++p) {
    int kl = p * 8 + rr;
    tile[kl][cc] = src[(size_t)(k0 + kl) * nsrc + n0 + cc];
  }
  __syncthreads();
#pragma unroll
  for (int p = 0; p < 4; ++p) {
    int nl = p * 8 + rr;
    dst[(size_t)(row0 + n0 + nl) * GK + k0 + cc] = f2bf(tile[cc][nl]);
  }
}

__global__ __launch_bounds__(256)
void k_prep(const float* __restrict__ x,  const float* __restrict__ Wq,
            const float* __restrict__ Wk, const float* __restrict__ Wv,
            const float* __restrict__ Wo, u16* __restrict__ xb,
            u16* __restrict__ WqkvT, u16* __restrict__ WoT,
            float2* __restrict__ tab) {
  __shared__ float tile[32][33];
  const int bid = blockIdx.x;
  if (bid < 8192) {                       // fp32 -> bf16 convert, 4 elems/thread
    int i = bid * 256 + threadIdx.x;
    f32x4 v = *(const f32x4*)(x + (size_t)i * 4);
    u16x4 o;
    o[0] = f2bf(v[0]); o[1] = f2bf(v[1]); o[2] = f2bf(v[2]); o[3] = f2bf(v[3]);
    *(u16x4*)(xb + (size_t)i * 4) = o;
  } else if (bid < 12288) {
    prep_transpose(Wq, 2048, WqkvT, 0,    bid - 8192,  tile);
  } else if (bid < 13312) {
    prep_transpose(Wk, 512,  WqkvT, 2048, bid - 12288, tile);
  } else if (bid < 14336) {
    prep_transpose(Wv, 512,  WqkvT, 2560, bid - 13312, tile);
  } else if (bid < 18432) {
    prep_transpose(Wo, 2048, WoT,   0,    bid - 14336, tile);
  } else {                                // rope cos/sin table
    int idx = (bid - 18432) * 256 + threadIdx.x;
    int t = idx >> 5, i = idx & 31;
    float inv = 1.0f / powf(10000.0f, (float)i / 32.0f);
    float ang = (float)t * inv;
    tab[idx] = make_float2(cosf(ang), sinf(ang));
  }
}

// ---------------- bf16 GEMM: C[M][N] = A[M][GK] * Bt[N][GK]^T ----------------
// 128x128 tile, BK=64, 4 waves (2x2), global_load_lds double-buffer,
// T2 XOR swizzle applied via pre-swizzled global source (linear LDS dest).
// MODE 0: bf16 out; q|k cols (<2560) get fused RoPE then -> QKV (stride 2560);
//         v cols (>=2560) -> transposed Vt ([b][kvh][d][t]).
// MODE 1: f32 out, stride N.
template <int MODE>
__global__ __launch_bounds__(256, 2)
void k_gemm(const u16* __restrict__ A, const u16* __restrict__ Bt,
            u16* __restrict__ QKV, u16* __restrict__ Vt, float* __restrict__ Cf,
            const float2* __restrict__ tab, int N) {
  __shared__ __align__(16) u16 lds[2][16384];   // per buf: A 128x64 | B 128x64
  const int tid = threadIdx.x;
  const int lane = tid & 63, wid = tid >> 6;
  const int nTN = N >> 7;
  const int tm = blockIdx.x / nTN, tn = blockIdx.x % nTN;
  const int m0 = tm << 7, n0 = tn << 7;
  const int l15 = lane & 15, lg = lane >> 4;
  const int wr = (wid >> 1) << 6, wc = (wid & 1) << 6;

  f32x4 acc[4][4] = {};

  auto stage = [&](int buf, int k0) {
    u16* base = &lds[buf][0];
#pragma unroll
    for (int p = 0; p < 4; ++p) {
      int c = p * 256 + tid;
      int row = c >> 3, kb = c & 7;
      int ksrc = k0 + ((kb ^ (row & 7)) << 3);   // inverse-swizzled source col
      const u16* sA = A + (size_t)(m0 + row) * GK + ksrc;
      __builtin_amdgcn_global_load_lds((gas_u32*)sA, (las_u32*)(base + c * 8), 16, 0, 0);
      const u16* sB = Bt + (size_t)(n0 + row) * GK + ksrc;
      __builtin_amdgcn_global_load_lds((gas_u32*)sB, (las_u32*)(base + 8192 + c * 8), 16, 0, 0);
    }
  };

  auto compute = [&](int buf) {
    const u16* ldsA = &lds[buf][0];
    const u16* ldsB = &lds[buf][8192];
#pragma unroll
    for (int kk = 0; kk < 2; ++kk) {
      bf16x8 af[4], bfr[4];
#pragma unroll
      for (int m = 0; m < 4; ++m) {
        int row = wr + m * 16 + l15;
        int koff = (kk * 32 + lg * 8) ^ ((row & 7) << 3);
        af[m] = *(const bf16x8*)(ldsA + row * 64 + koff);
      }
#pragma unroll
      for (int n = 0; n < 4; ++n) {
        int row = wc + n * 16 + l15;
        int koff = (kk * 32 + lg * 8) ^ ((row & 7) << 3);
        bfr[n] = *(const bf16x8*)(ldsB + row * 64 + koff);
      }
#pragma unroll
      for (int m = 0; m < 4; ++m)
#pragma unroll
        for (int n = 0; n < 4; ++n)
          acc[m][n] = __builtin_amdgcn_mfma_f32_16x16x32_bf16(af[m], bfr[n], acc[m][n], 0, 0, 0);
    }
  };

  stage(0, 0);
  __syncthreads();
  const int nk = GK / 64;
  for (int t = 0; t < nk; ++t) {
    if (t + 1 < nk) stage((t + 1) & 1, (t + 1) * 64);
    compute(t & 1);
    __syncthreads();
  }

  if (MODE == 1) {
#pragma unroll
    for (int m = 0; m < 4; ++m)
#pragma unroll
      for (int n = 0; n < 4; ++n)
#pragma unroll
        for (int r = 0; r < 4; ++r) {
          int row = m0 + wr + m * 16 + lg * 4 + r;
          int col = n0 + wc + n * 16 + l15;
          Cf[(size_t)row * N + col] = acc[m][n][r];
        }
  } else if (n0 >= 2560) {   // V tile -> transposed Vt[b][kvh][d][t]
#pragma unroll
    for (int m = 0; m < 4; ++m)
#pragma unroll
      for (int n = 0; n < 4; ++n)
#pragma unroll
        for (int r = 0; r < 4; ++r) {
          int row = m0 + wr + m * 16 + lg * 4 + r;
          int col = n0 + wc + n * 16 + l15;
          int dh = col - 2560, kvh = dh >> 6, d = dh & 63;
          int bb = row >> 11, tt = row & 2047;
          Vt[(((size_t)bb * NKV + kvh) * 64 + d) * TQ + tt] = f2bf(acc[m][n][r]);
        }
  } else {                   // q|k tile: fused RoPE (pair partner via shfl_xor 1)
#pragma unroll
    for (int m = 0; m < 4; ++m)
#pragma unroll
      for (int n = 0; n < 4; ++n) {
        int col = n0 + wc + n * 16 + l15;
        int dh = (col & 63) >> 1;
        float sgn = (col & 1) ? 1.0f : -1.0f;
#pragma unroll
        for (int r = 0; r < 4; ++r) {
          int row = m0 + wr + m * 16 + lg * 4 + r;
          float a = acc[m][n][r];
          float b = __shfl_xor(a, 1);
          int t = row & (TQ - 1);
          float2 csv = tab[t * 32 + dh];
          float o = a * csv.x + sgn * b * csv.y;
          QKV[(size_t)row * QK_W + col] = f2bf(o);
        }
      }
  }
}

// ---------------- causal GQA flash attention (round-4 proven version) ----------------
// block = (b,h,q-tile of 128). 4 waves x 32 q rows. KVBLK=64.
// Swapped orientation: S^T = mfma(K,Q), lane owns full softmax rows (q=l15);
// O^T = mfma(V^T,P). Double-buffered global_load_lds staging, one barrier/tile.
// Raw-score softmax with exp2 folding; defer-max (raw thr 64 = e^8); cvtpk P-store.
__global__ __launch_bounds__(256, 3)
void k_attn(const u16* __restrict__ QKV, const u16* __restrict__ Vt, u16* __restrict__ ctx) {
  __shared__ __align__(16) u16 Ksh[2][4096];   // [kv 64][d 64] col-swizzled
  __shared__ __align__(16) u16 Vsh[2][4096];   // [d 64][t 64] col-swizzled
  __shared__ __align__(16) u16 Psh[4][2048];   // per-wave [32 q][64 kv] swizzled
  const int tid = threadIdx.x, lane = tid & 63, w = tid >> 6;
  const int l15 = lane & 15, lg = lane >> 4;
  const int bid = blockIdx.x;
  const int qt = 15 - (bid >> 6);              // heavy-first
  const int hb = bid & 63;
  const int h = hb & 31, b = hb >> 5;
  const int kvh = h >> 2;                      // G=4
  const int q0 = qt << 7;
  const int qb = q0 + w * 32;                  // this wave's first q row
  const size_t rowbase = (size_t)b * TQ;
  const u16* Vg = Vt + ((size_t)(b * NKV + kvh)) * 64 * TQ;

  auto stage = [&](int buf, int kv0) {
    u16* kd = &Ksh[buf][0];
    u16* vd = &Vsh[buf][0];
#pragma unroll
    for (int p = 0; p < 2; ++p) {
      int c = p * 256 + tid;
      int row = c >> 3, kb = c & 7;
      int off = (kb ^ (row & 7)) << 3;
      const u16* sK = QKV + (rowbase + kv0 + row) * QK_W + 2048 + kvh * 64 + off;
      __builtin_amdgcn_global_load_lds((gas_u32*)sK, (las_u32*)(kd + c * 8), 16, 0, 0);
      const u16* sV = Vg + (size_t)row * TQ + kv0 + off;
      __builtin_amdgcn_global_load_lds((gas_u32*)sV, (las_u32*)(vd + c * 8), 16, 0, 0);
    }
  };

  bf16x8 qf[2][2];
#pragma unroll
  for (int m = 0; m < 2; ++m)
#pragma unroll
    for (int kk = 0; kk < 2; ++kk)
      qf[m][kk] = *(const bf16x8*)(QKV + (rowbase + qb + m * 16 + l15) * QK_W + h * 64 + kk * 32 + lg * 8);

  float m_run[2] = {NEG, NEG}, l_run[2] = {0.f, 0.f};
  f32x4 oacc[2][4] = {};

  stage(0, 0);
  const int nt = 2 * qt + 2;
  for (int t = 0; t < nt; ++t) {
    const int kv0 = t << 6;
    __syncthreads();                  // drains vmcnt(0): buf[t&1] ready block-wide
    if (t + 1 < nt) stage((t + 1) & 1, kv0 + 64);
    if (kv0 > qb + 31) continue;      // this wave fully above diagonal for this tile

    const u16* Kl = &Ksh[t & 1][0];
    const u16* Vl = &Vsh[t & 1][0];

    // S^T = K * Q (raw scores): lane owns col q = qb+m*16+l15, row kv = kv0+c*16+lg*4+r
    f32x4 stv[2][4];
#pragma unroll
    for (int c = 0; c < 4; ++c) {
      const int krow = c * 16 + l15;
      const int ks = (krow & 7) << 3;
      f32x4 z0 = {}, z1 = {};
#pragma unroll
      for (int kk = 0; kk < 2; ++kk) {
        bf16x8 kf = *(const bf16x8*)(Kl + krow * 64 + ((kk * 32 + lg * 8) ^ ks));
        z0 = __builtin_amdgcn_mfma_f32_16x16x32_bf16(kf, qf[0][kk], z0, 0, 0, 0);
        z1 = __builtin_amdgcn_mfma_f32_16x16x32_bf16(kf, qf[1][kk], z1, 0, 0, 0);
      }
      stv[0][c] = z0; stv[1][c] = z1;
    }

    const bool maskT = (kv0 + 63 > qb);
    float mt[2];
    if (maskT) {
#pragma unroll
      for (int m = 0; m < 2; ++m) {
        const int qpos = qb + m * 16 + l15;
        float mx = NEG;
#pragma unroll
        for (int c = 0; c < 4; ++c)
#pragma unroll
          for (int r = 0; r < 4; ++r) {
            int kvpos = kv0 + c * 16 + lg * 4 + r;
            float sv = stv[m][c][r];
            sv = (kvpos > qpos) ? NEG : sv;
            stv[m][c][r] = sv;
            mx = fmaxf(mx, sv);
          }
        mt[m] = mx;
      }
    } else {
#pragma unroll
      for (int m = 0; m < 2; ++m) {
        float mx = NEG;
#pragma unroll
        for (int c = 0; c < 4; ++c)
#pragma unroll
          for (int r = 0; r < 4; ++r) mx = fmaxf(mx, stv[m][c][r]);
        mt[m] = mx;
      }
    }
#pragma unroll
    for (int m = 0; m < 2; ++m) {
      mt[m] = fmaxf(mt[m], __shfl_xor(mt[m], 16));
      mt[m] = fmaxf(mt[m], __shfl_xor(mt[m], 32));
    }

    // defer-max: rescale only when some row grew past raw-threshold 64 (= e^8)
    if (__any((mt[0] > m_run[0] + 64.0f) || (mt[1] > m_run[1] + 64.0f))) {
#pragma unroll
      for (int m = 0; m < 2; ++m) {
        float nm = fmaxf(m_run[m], mt[m]);
        float sc = exp2g((m_run[m] - nm) * CL2);
        m_run[m] = nm;
        l_run[m] *= sc;
#pragma unroll
        for (int dt = 0; dt < 4; ++dt) oacc[m][dt] *= sc;
      }
    }

    // P = exp2(S*CL2 - m*CL2) -> bf16 per-wave LDS [q][kv] (swizzled), row-sum
    u16* Pw = &Psh[w][0];
#pragma unroll
    for (int m = 0; m < 2; ++m) {
      const float msc = m_run[m] * CL2;
      float ssum = 0.f;
      const int rowp = m * 16 + l15;
      const int swz = (l15 & 7) << 3;
#pragma unroll
      for (int c = 0; c < 4; ++c) {
        float p0 = exp2g(stv[m][c][0] * CL2 - msc);
        float p1 = exp2g(stv[m][c][1] * CL2 - msc);
        float p2 = exp2g(stv[m][c][2] * CL2 - msc);
        float p3 = exp2g(stv[m][c][3] * CL2 - msc);
        ssum += (p0 + p1) + (p2 + p3);
        const int kvb = (c * 16 + lg * 4) ^ swz;
        *(u32*)(Pw + rowp * 64 + kvb)       = cvtpk(p0, p1);
        *(u32*)(Pw + rowp * 64 + (kvb | 2)) = cvtpk(p2, p3);
      }
      ssum += __shfl_xor(ssum, 16);
      ssum += __shfl_xor(ssum, 32);
      l_run[m] += ssum;
    }

    // O^T += V^T * P : lane owns O^T[d = dt*16+lg*4+r][q = l15]
    bf16x8 pf[2][2];
#pragma unroll
    for (int m = 0; m < 2; ++m)
#pragma unroll
      for (int kc = 0; kc < 2; ++kc)
        pf[m][kc] = *(const bf16x8*)(Pw + (m * 16 + l15) * 64 + ((kc * 32 + lg * 8) ^ ((l15 & 7) << 3)));
#pragma unroll
    for (int dt = 0; dt < 4; ++dt) {
      const int vrow = dt * 16 + l15;
      const int vs = (vrow & 7) << 3;
#pragma unroll
      for (int kc = 0; kc < 2; ++kc) {
        bf16x8 vf = *(const bf16x8*)(Vl + vrow * 64 + ((kc * 32 + lg * 8) ^ vs));
        oacc[0][dt] = __builtin_amdgcn_mfma_f32_16x16x32_bf16(vf, pf[0][kc], oacc[0][dt], 0, 0, 0);
        oacc[1][dt] = __builtin_amdgcn_mfma_f32_16x16x32_bf16(vf, pf[1][kc], oacc[1][dt], 0, 0, 0);
      }
    }
  }

  // epilogue: normalize, write ctx[q][h*64+d] as u32 pairs
#pragma unroll
  for (int m = 0; m < 2; ++m) {
    float inv = 1.0f / l_run[m];
    size_t row = rowbase + qb + m * 16 + l15;
#pragma unroll
    for (int dt = 0; dt < 4; ++dt) {
      int col = h * 64 + dt * 16 + lg * 4;
      u32 w0 = cvtpk(oacc[m][dt][0] * inv, oacc[m][dt][1] * inv);
      u32 w1 = cvtpk(oacc[m][dt][2] * inv, oacc[m][dt][3] * inv);
      *(u32*)(ctx + row * DOUT + col) = w0;
      *(u32*)(ctx + row * DOUT + col + 2) = w1;
    }
  }
}

// ---------------- host launcher ----------------
extern "C" void kernel_launch(void* const* d_in, const int* in_sizes, int n_in,
                              void* d_out, int out_size, void* d_ws, size_t ws_size,
                              hipStream_t stream) {
  const float* x  = (const float*)d_in[0];
  const float* Wq = (const float*)d_in[1];
  const float* Wk = (const float*)d_in[2];
  const float* Wv = (const float*)d_in[3];
  const float* Wo = (const float*)d_in[4];
  float* out = (float*)d_out;

  char* ws = (char*)d_ws;
  size_t off = 0;
  auto alloc = [&](size_t bytes) -> void* {
    void* p = ws + off;
    off += (bytes + 255) & ~(size_t)255;
    return p;
  };
  const int rows = NB * TQ;  // 4096
  u16*    xb    = (u16*)alloc((size_t)rows * DIN * 2);
  u16*    WqkvT = (u16*)alloc((size_t)NQKV * GK * 2);
  u16*    WoT   = (u16*)alloc((size_t)DOUT * GK * 2);
  u16*    QKV   = (u16*)alloc((size_t)rows * QK_W * 2);
  u16*    Vt    = (u16*)alloc((size_t)NB * NKV * 64 * TQ * 2);
  u16*    ctx   = (u16*)alloc((size_t)rows * DOUT * 2);
  float2* tab   = (float2*)alloc((size_t)TQ * 32 * sizeof(float2));

  k_prep<<<dim3(18688), dim3(256), 0, stream>>>(x, Wq, Wk, Wv, Wo, xb, WqkvT, WoT, tab);
  k_gemm<0><<<dim3((rows / 128) * (NQKV / 128)), dim3(256), 0, stream>>>(xb, WqkvT, QKV, Vt, nullptr, tab, NQKV);
  k_attn<<<dim3(NB * NH * (TQ / 128)), dim3(256), 0, stream>>>(QKV, Vt, ctx);
  k_gemm<1><<<dim3((rows / 128) * (DOUT / 128)), dim3(256), 0, stream>>>(ctx, WoT, nullptr, nullptr, out, nullptr, DOUT);
}

// Round 14
// 181.497 us; speedup vs baseline: 1.5626x; 1.0160x over previous
//
#include <hip/hip_runtime.h>

#define TQ 2048
#define NB 2
#define NH 32
#define NKV 8
#define HD 64
#define DIN 2048
#define DOUT 2048
#define NQKV 3072   // GEMM N: 2048 q | 512 k | 512 v
#define QK_W 2560   // QKV buffer row width (q|k only; v split out)
#define GK 2048     // K dim of both GEMMs

typedef unsigned short u16;
typedef unsigned int u32;
typedef __attribute__((ext_vector_type(8))) short bf16x8;
typedef __attribute__((ext_vector_type(4))) float f32x4;
typedef __attribute__((ext_vector_type(4))) u16 u16x4;

typedef __attribute__((address_space(1))) const u32 gas_u32;
typedef __attribute__((address_space(3))) u32 las_u32;

#define NEG (-1.0e30f)
#define CL2 0.18033688f   // 0.125 * log2(e)

__device__ __forceinline__ u16 f2bf(float f) {
  u32 u = __float_as_uint(f);
  u += 0x7fffu + ((u >> 16) & 1u);
  return (u16)(u >> 16);
}
__device__ __forceinline__ float bf2f(u16 h) { return __uint_as_float(((u32)h) << 16); }
__device__ __forceinline__ u32 cvtpk(float lo, float hi) {
  u32 r;
  asm("v_cvt_pk_bf16_f32 %0, %1, %2" : "=v"(r) : "v"(lo), "v"(hi));
  return r;
}
// native exp2; s_nop covers the TRANS->consumer wait state the compiler
// cannot insert around opaque inline asm.
__device__ __forceinline__ float exp2g(float x) {
  float r;
  asm("v_exp_f32 %0, %1\n\ts_nop 0" : "=v"(r) : "v"(x));
  return r;
}

// =============== fused prep: cvt | 4x transpose | rope table ===============
// All six prep tasks are mutually independent; one launch lets them overlap
// across CUs instead of serializing as separate graph nodes.
// Block ranges: [0,8192) cvt; [8192,12288) Wq^T; [12288,13312) Wk^T;
// [13312,14336) Wv^T; [14336,18432) Wo^T; [18432,18688) rope table.
__device__ __forceinline__ void prep_transpose(const float* __restrict__ src, int nsrc,
                                               u16* __restrict__ dst, int row0, int vb,
                                               float (*tile)[33]) {
  const int nTK = GK / 32;
  int kt = vb % nTK, nt = vb / nTK;
  int k0 = kt * 32, n0 = nt * 32;
  int rr = threadIdx.x >> 5, cc = threadIdx.x & 31;
#pragma unroll
  for (int p = 0; p < 4; ++p) {
    int kl = p * 8 + rr;
    tile[kl][cc] = src[(size_t)(k0 + kl) * nsrc + n0 + cc];
  }
  __syncthreads();
#pragma unroll
  for (int p = 0; p < 4; ++p) {
    int nl = p * 8 + rr;
    dst[(size_t)(row0 + n0 + nl) * GK + k0 + cc] = f2bf(tile[cc][nl]);
  }
}

__global__ __launch_bounds__(256)
void k_prep(const float* __restrict__ x,  const float* __restrict__ Wq,
            const float* __restrict__ Wk, const float* __restrict__ Wv,
            const float* __restrict__ Wo, u16* __restrict__ xb,
            u16* __restrict__ WqkvT, u16* __restrict__ WoT,
            float2* __restrict__ tab) {
  __shared__ float tile[32][33];
  const int bid = blockIdx.x;
  if (bid < 8192) {                       // fp32 -> bf16 convert, 4 elems/thread
    int i = bid * 256 + threadIdx.x;
    f32x4 v = *(const f32x4*)(x + (size_t)i * 4);
    u16x4 o;
    o[0] = f2bf(v[0]); o[1] = f2bf(v[1]); o[2] = f2bf(v[2]); o[3] = f2bf(v[3]);
    *(u16x4*)(xb + (size_t)i * 4) = o;
  } else if (bid < 12288) {
    prep_transpose(Wq, 2048, WqkvT, 0,    bid - 8192,  tile);
  } else if (bid < 13312) {
    prep_transpose(Wk, 512,  WqkvT, 2048, bid - 12288, tile);
  } else if (bid < 14336) {
    prep_transpose(Wv, 512,  WqkvT, 2560, bid - 13312, tile);
  } else if (bid < 18432) {
    prep_transpose(Wo, 2048, WoT,   0,    bid - 14336, tile);
  } else {                                // rope cos/sin table
    int idx = (bid - 18432) * 256 + threadIdx.x;
    int t = idx >> 5, i = idx & 31;
    float inv = 1.0f / powf(10000.0f, (float)i / 32.0f);
    float ang = (float)t * inv;
    tab[idx] = make_float2(cosf(ang), sinf(ang));
  }
}

// ---------------- bf16 GEMM: C[M][N] = A[M][GK] * Bt[N][GK]^T ----------------
// 128x128 tile, BK=64, 4 waves (2x2), global_load_lds double-buffer,
// T2 XOR swizzle applied via pre-swizzled global source (linear LDS dest).
// T1 XCD-chunked blockIdx swizzle (grids are %8==0 -> bijective): each XCD gets
// a contiguous tm-band so its 4 A-panels stay L2-resident across the tn sweep
// (FETCH showed 54 MB of HBM panel re-fetch without it).
// MODE 0: bf16 out; q|k cols (<2560) get fused RoPE then -> QKV (stride 2560);
//         v cols (>=2560) -> transposed Vt ([b][kvh][d][t]).
// MODE 1: f32 out, stride N.
template <int MODE>
__global__ __launch_bounds__(256, 2)
void k_gemm(const u16* __restrict__ A, const u16* __restrict__ Bt,
            u16* __restrict__ QKV, u16* __restrict__ Vt, float* __restrict__ Cf,
            const float2* __restrict__ tab, int N) {
  __shared__ __align__(16) u16 lds[2][16384];   // per buf: A 128x64 | B 128x64
  const int tid = threadIdx.x;
  const int lane = tid & 63, wid = tid >> 6;
  const int nTN = N >> 7;
  const int cpx = gridDim.x >> 3;               // blocks per XCD chunk
  const int bid = (blockIdx.x & 7) * cpx + (blockIdx.x >> 3);  // T1 chunked swizzle
  const int tm = bid / nTN, tn = bid % nTN;
  const int m0 = tm << 7, n0 = tn << 7;
  const int l15 = lane & 15, lg = lane >> 4;
  const int wr = (wid >> 1) << 6, wc = (wid & 1) << 6;

  f32x4 acc[4][4] = {};

  auto stage = [&](int buf, int k0) {
    u16* base = &lds[buf][0];
#pragma unroll
    for (int p = 0; p < 4; ++p) {
      int c = p * 256 + tid;
      int row = c >> 3, kb = c & 7;
      int ksrc = k0 + ((kb ^ (row & 7)) << 3);   // inverse-swizzled source col
      const u16* sA = A + (size_t)(m0 + row) * GK + ksrc;
      __builtin_amdgcn_global_load_lds((gas_u32*)sA, (las_u32*)(base + c * 8), 16, 0, 0);
      const u16* sB = Bt + (size_t)(n0 + row) * GK + ksrc;
      __builtin_amdgcn_global_load_lds((gas_u32*)sB, (las_u32*)(base + 8192 + c * 8), 16, 0, 0);
    }
  };

  auto compute = [&](int buf) {
    const u16* ldsA = &lds[buf][0];
    const u16* ldsB = &lds[buf][8192];
#pragma unroll
    for (int kk = 0; kk < 2; ++kk) {
      bf16x8 af[4], bfr[4];
#pragma unroll
      for (int m = 0; m < 4; ++m) {
        int row = wr + m * 16 + l15;
        int koff = (kk * 32 + lg * 8) ^ ((row & 7) << 3);
        af[m] = *(const bf16x8*)(ldsA + row * 64 + koff);
      }
#pragma unroll
      for (int n = 0; n < 4; ++n) {
        int row = wc + n * 16 + l15;
        int koff = (kk * 32 + lg * 8) ^ ((row & 7) << 3);
        bfr[n] = *(const bf16x8*)(ldsB + row * 64 + koff);
      }
#pragma unroll
      for (int m = 0; m < 4; ++m)
#pragma unroll
        for (int n = 0; n < 4; ++n)
          acc[m][n] = __builtin_amdgcn_mfma_f32_16x16x32_bf16(af[m], bfr[n], acc[m][n], 0, 0, 0);
    }
  };

  stage(0, 0);
  __syncthreads();
  const int nk = GK / 64;
  for (int t = 0; t < nk; ++t) {
    if (t + 1 < nk) stage((t + 1) & 1, (t + 1) * 64);
    compute(t & 1);
    __syncthreads();
  }

  if (MODE == 1) {
#pragma unroll
    for (int m = 0; m < 4; ++m)
#pragma unroll
      for (int n = 0; n < 4; ++n)
#pragma unroll
        for (int r = 0; r < 4; ++r) {
          int row = m0 + wr + m * 16 + lg * 4 + r;
          int col = n0 + wc + n * 16 + l15;
          Cf[(size_t)row * N + col] = acc[m][n][r];
        }
  } else if (n0 >= 2560) {   // V tile -> transposed Vt[b][kvh][d][t]
#pragma unroll
    for (int m = 0; m < 4; ++m)
#pragma unroll
      for (int n = 0; n < 4; ++n)
#pragma unroll
        for (int r = 0; r < 4; ++r) {
          int row = m0 + wr + m * 16 + lg * 4 + r;
          int col = n0 + wc + n * 16 + l15;
          int dh = col - 2560, kvh = dh >> 6, d = dh & 63;
          int bb = row >> 11, tt = row & 2047;
          Vt[(((size_t)bb * NKV + kvh) * 64 + d) * TQ + tt] = f2bf(acc[m][n][r]);
        }
  } else {                   // q|k tile: fused RoPE (pair partner via shfl_xor 1)
#pragma unroll
    for (int m = 0; m < 4; ++m)
#pragma unroll
      for (int n = 0; n < 4; ++n) {
        int col = n0 + wc + n * 16 + l15;
        int dh = (col & 63) >> 1;
        float sgn = (col & 1) ? 1.0f : -1.0f;
#pragma unroll
        for (int r = 0; r < 4; ++r) {
          int row = m0 + wr + m * 16 + lg * 4 + r;
          float a = acc[m][n][r];
          float b = __shfl_xor(a, 1);
          int t = row & (TQ - 1);
          float2 csv = tab[t * 32 + dh];
          float o = a * csv.x + sgn * b * csv.y;
          QKV[(size_t)row * QK_W + col] = f2bf(o);
        }
      }
  }
}

// ---------------- causal GQA flash attention (round-4 proven version) ----------------
// block = (b,h,q-tile of 128). 4 waves x 32 q rows. KVBLK=64.
// Swapped orientation: S^T = mfma(K,Q), lane owns full softmax rows (q=l15);
// O^T = mfma(V^T,P). Double-buffered global_load_lds staging, one barrier/tile.
// Raw-score softmax with exp2 folding; defer-max (raw thr 64 = e^8); cvtpk P-store.
// No XCD swizzle here: it would break the heavy-first LPT balance (r12 lesson:
// grid depth + inter-block overlap dominate for causal attention).
__global__ __launch_bounds__(256, 3)
void k_attn(const u16* __restrict__ QKV, const u16* __restrict__ Vt, u16* __restrict__ ctx) {
  __shared__ __align__(16) u16 Ksh[2][4096];   // [kv 64][d 64] col-swizzled
  __shared__ __align__(16) u16 Vsh[2][4096];   // [d 64][t 64] col-swizzled
  __shared__ __align__(16) u16 Psh[4][2048];   // per-wave [32 q][64 kv] swizzled
  const int tid = threadIdx.x, lane = tid & 63, w = tid >> 6;
  const int l15 = lane & 15, lg = lane >> 4;
  const int bid = blockIdx.x;
  const int qt = 15 - (bid >> 6);              // heavy-first
  const int hb = bid & 63;
  const int h = hb & 31, b = hb >> 5;
  const int kvh = h >> 2;                      // G=4
  const int q0 = qt << 7;
  const int qb = q0 + w * 32;                  // this wave's first q row
  const size_t rowbase = (size_t)b * TQ;
  const u16* Vg = Vt + ((size_t)(b * NKV + kvh)) * 64 * TQ;

  auto stage = [&](int buf, int kv0) {
    u16* kd = &Ksh[buf][0];
    u16* vd = &Vsh[buf][0];
#pragma unroll
    for (int p = 0; p < 2; ++p) {
      int c = p * 256 + tid;
      int row = c >> 3, kb = c & 7;
      int off = (kb ^ (row & 7)) << 3;
      const u16* sK = QKV + (rowbase + kv0 + row) * QK_W + 2048 + kvh * 64 + off;
      __builtin_amdgcn_global_load_lds((gas_u32*)sK, (las_u32*)(kd + c * 8), 16, 0, 0);
      const u16* sV = Vg + (size_t)row * TQ + kv0 + off;
      __builtin_amdgcn_global_load_lds((gas_u32*)sV, (las_u32*)(vd + c * 8), 16, 0, 0);
    }
  };

  bf16x8 qf[2][2];
#pragma unroll
  for (int m = 0; m < 2; ++m)
#pragma unroll
    for (int kk = 0; kk < 2; ++kk)
      qf[m][kk] = *(const bf16x8*)(QKV + (rowbase + qb + m * 16 + l15) * QK_W + h * 64 + kk * 32 + lg * 8);

  float m_run[2] = {NEG, NEG}, l_run[2] = {0.f, 0.f};
  f32x4 oacc[2][4] = {};

  stage(0, 0);
  const int nt = 2 * qt + 2;
  for (int t = 0; t < nt; ++t) {
    const int kv0 = t << 6;
    __syncthreads();                  // drains vmcnt(0): buf[t&1] ready block-wide
    if (t + 1 < nt) stage((t + 1) & 1, kv0 + 64);
    if (kv0 > qb + 31) continue;      // this wave fully above diagonal for this tile

    const u16* Kl = &Ksh[t & 1][0];
    const u16* Vl = &Vsh[t & 1][0];

    // S^T = K * Q (raw scores): lane owns col q = qb+m*16+l15, row kv = kv0+c*16+lg*4+r
    f32x4 stv[2][4];
#pragma unroll
    for (int c = 0; c < 4; ++c) {
      const int krow = c * 16 + l15;
      const int ks = (krow & 7) << 3;
      f32x4 z0 = {}, z1 = {};
#pragma unroll
      for (int kk = 0; kk < 2; ++kk) {
        bf16x8 kf = *(const bf16x8*)(Kl + krow * 64 + ((kk * 32 + lg * 8) ^ ks));
        z0 = __builtin_amdgcn_mfma_f32_16x16x32_bf16(kf, qf[0][kk], z0, 0, 0, 0);
        z1 = __builtin_amdgcn_mfma_f32_16x16x32_bf16(kf, qf[1][kk], z1, 0, 0, 0);
      }
      stv[0][c] = z0; stv[1][c] = z1;
    }

    const bool maskT = (kv0 + 63 > qb);
    float mt[2];
    if (maskT) {
#pragma unroll
      for (int m = 0; m < 2; ++m) {
        const int qpos = qb + m * 16 + l15;
        float mx = NEG;
#pragma unroll
        for (int c = 0; c < 4; ++c)
#pragma unroll
          for (int r = 0; r < 4; ++r) {
            int kvpos = kv0 + c * 16 + lg * 4 + r;
            float sv = stv[m][c][r];
            sv = (kvpos > qpos) ? NEG : sv;
            stv[m][c][r] = sv;
            mx = fmaxf(mx, sv);
          }
        mt[m] = mx;
      }
    } else {
#pragma unroll
      for (int m = 0; m < 2; ++m) {
        float mx = NEG;
#pragma unroll
        for (int c = 0; c < 4; ++c)
#pragma unroll
          for (int r = 0; r < 4; ++r) mx = fmaxf(mx, stv[m][c][r]);
        mt[m] = mx;
      }
    }
#pragma unroll
    for (int m = 0; m < 2; ++m) {
      mt[m] = fmaxf(mt[m], __shfl_xor(mt[m], 16));
      mt[m] = fmaxf(mt[m], __shfl_xor(mt[m], 32));
    }

    // defer-max: rescale only when some row grew past raw-threshold 64 (= e^8)
    if (__any((mt[0] > m_run[0] + 64.0f) || (mt[1] > m_run[1] + 64.0f))) {
#pragma unroll
      for (int m = 0; m < 2; ++m) {
        float nm = fmaxf(m_run[m], mt[m]);
        float sc = exp2g((m_run[m] - nm) * CL2);
        m_run[m] = nm;
        l_run[m] *= sc;
#pragma unroll
        for (int dt = 0; dt < 4; ++dt) oacc[m][dt] *= sc;
      }
    }

    // P = exp2(S*CL2 - m*CL2) -> bf16 per-wave LDS [q][kv] (swizzled), row-sum
    u16* Pw = &Psh[w][0];
#pragma unroll
    for (int m = 0; m < 2; ++m) {
      const float msc = m_run[m] * CL2;
      float ssum = 0.f;
      const int rowp = m * 16 + l15;
      const int swz = (l15 & 7) << 3;
#pragma unroll
      for (int c = 0; c < 4; ++c) {
        float p0 = exp2g(stv[m][c][0] * CL2 - msc);
        float p1 = exp2g(stv[m][c][1] * CL2 - msc);
        float p2 = exp2g(stv[m][c][2] * CL2 - msc);
        float p3 = exp2g(stv[m][c][3] * CL2 - msc);
        ssum += (p0 + p1) + (p2 + p3);
        const int kvb = (c * 16 + lg * 4) ^ swz;
        *(u32*)(Pw + rowp * 64 + kvb)       = cvtpk(p0, p1);
        *(u32*)(Pw + rowp * 64 + (kvb | 2)) = cvtpk(p2, p3);
      }
      ssum += __shfl_xor(ssum, 16);
      ssum += __shfl_xor(ssum, 32);
      l_run[m] += ssum;
    }

    // O^T += V^T * P : lane owns O^T[d = dt*16+lg*4+r][q = l15]
    bf16x8 pf[2][2];
#pragma unroll
    for (int m = 0; m < 2; ++m)
#pragma unroll
      for (int kc = 0; kc < 2; ++kc)
        pf[m][kc] = *(const bf16x8*)(Pw + (m * 16 + l15) * 64 + ((kc * 32 + lg * 8) ^ ((l15 & 7) << 3)));
#pragma unroll
    for (int dt = 0; dt < 4; ++dt) {
      const int vrow = dt * 16 + l15;
      const int vs = (vrow & 7) << 3;
#pragma unroll
      for (int kc = 0; kc < 2; ++kc) {
        bf16x8 vf = *(const bf16x8*)(Vl + vrow * 64 + ((kc * 32 + lg * 8) ^ vs));
        oacc[0][dt] = __builtin_amdgcn_mfma_f32_16x16x32_bf16(vf, pf[0][kc], oacc[0][dt], 0, 0, 0);
        oacc[1][dt] = __builtin_amdgcn_mfma_f32_16x16x32_bf16(vf, pf[1][kc], oacc[1][dt], 0, 0, 0);
      }
    }
  }

  // epilogue: normalize, write ctx[q][h*64+d] as u32 pairs
#pragma unroll
  for (int m = 0; m < 2; ++m) {
    float inv = 1.0f / l_run[m];
    size_t row = rowbase + qb + m * 16 + l15;
#pragma unroll
    for (int dt = 0; dt < 4; ++dt) {
      int col = h * 64 + dt * 16 + lg * 4;
      u32 w0 = cvtpk(oacc[m][dt][0] * inv, oacc[m][dt][1] * inv);
      u32 w1 = cvtpk(oacc[m][dt][2] * inv, oacc[m][dt][3] * inv);
      *(u32*)(ctx + row * DOUT + col) = w0;
      *(u32*)(ctx + row * DOUT + col + 2) = w1;
    }
  }
}

// ---------------- host launcher ----------------
extern "C" void kernel_launch(void* const* d_in, const int* in_sizes, int n_in,
                              void* d_out, int out_size, void* d_ws, size_t ws_size,
                              hipStream_t stream) {
  const float* x  = (const float*)d_in[0];
  const float* Wq = (const float*)d_in[1];
  const float* Wk = (const float*)d_in[2];
  const float* Wv = (const float*)d_in[3];
  const float* Wo = (const float*)d_in[4];
  float* out = (float*)d_out;

  char* ws = (char*)d_ws;
  size_t off = 0;
  auto alloc = [&](size_t bytes) -> void* {
    void* p = ws + off;
    off += (bytes + 255) & ~(size_t)255;
    return p;
  };
  const int rows = NB * TQ;  // 4096
  u16*    xb    = (u16*)alloc((size_t)rows * DIN * 2);
  u16*    WqkvT = (u16*)alloc((size_t)NQKV * GK * 2);
  u16*    WoT   = (u16*)alloc((size_t)DOUT * GK * 2);
  u16*    QKV   = (u16*)alloc((size_t)rows * QK_W * 2);
  u16*    Vt    = (u16*)alloc((size_t)NB * NKV * 64 * TQ * 2);
  u16*    ctx   = (u16*)alloc((size_t)rows * DOUT * 2);
  float2* tab   = (float2*)alloc((size_t)TQ * 32 * sizeof(float2));

  k_prep<<<dim3(18688), dim3(256), 0, stream>>>(x, Wq, Wk, Wv, Wo, xb, WqkvT, WoT, tab);
  k_gemm<0><<<dim3((rows / 128) * (NQKV / 128)), dim3(256), 0, stream>>>(xb, WqkvT, QKV, Vt, nullptr, tab, NQKV);
  k_attn<<<dim3(NB * NH * (TQ / 128)), dim3(256), 0, stream>>>(QKV, Vt, ctx);
  k_gemm<1><<<dim3((rows / 128) * (DOUT / 128)), dim3(256), 0, stream>>>(ctx, WoT, nullptr, nullptr, out, nullptr, DOUT);
}

// Round 16
// 180.894 us; speedup vs baseline: 1.5678x; 1.0033x over previous
//
#include <hip/hip_runtime.h>

#define TQ 2048
#define NB 2
#define NH 32
#define NKV 8
#define HD 64
#define DIN 2048
#define DOUT 2048
#define NQKV 3072   // GEMM N: 2048 q | 512 k | 512 v
#define QK_W 2560   // QKV buffer row width (q|k only; v split out)
#define GK 2048     // K dim of both GEMMs

typedef unsigned short u16;
typedef unsigned int u32;
typedef __attribute__((ext_vector_type(8))) short bf16x8;
typedef __attribute__((ext_vector_type(4))) float f32x4;
typedef __attribute__((ext_vector_type(4))) u16 u16x4;

typedef __attribute__((address_space(1))) const u32 gas_u32;
typedef __attribute__((address_space(3))) u32 las_u32;

#define NEG (-1.0e30f)
#define CL2 0.18033688f   // 0.125 * log2(e)

__device__ __forceinline__ u16 f2bf(float f) {
  u32 u = __float_as_uint(f);
  u += 0x7fffu + ((u >> 16) & 1u);
  return (u16)(u >> 16);
}
__device__ __forceinline__ float bf2f(u16 h) { return __uint_as_float(((u32)h) << 16); }
__device__ __forceinline__ u32 cvtpk(float lo, float hi) {
  u32 r;
  asm("v_cvt_pk_bf16_f32 %0, %1, %2" : "=v"(r) : "v"(lo), "v"(hi));
  return r;
}
// native exp2; the s_nop covers the TRANS->consumer wait state. PROVEN FORM —
// round-15 showed replacing this with __builtin_amdgcn_exp2f corrupts results
// (sc came back ~argument scale, output ~1e30). Do not "simplify" this.
__device__ __forceinline__ float exp2g(float x) {
  float r;
  asm("v_exp_f32 %0, %1\n\ts_nop 0" : "=v"(r) : "v"(x));
  return r;
}

// =============== fused prep: cvt | 4x transpose | rope table ===============
// All six prep tasks are mutually independent; one launch lets them overlap
// across CUs instead of serializing as separate graph nodes.
// Block ranges: [0,8192) cvt; [8192,12288) Wq^T; [12288,13312) Wk^T;
// [13312,14336) Wv^T; [14336,18432) Wo^T; [18432,18688) rope table.
__device__ __forceinline__ void prep_transpose(const float* __restrict__ src, int nsrc,
                                               u16* __restrict__ dst, int row0, int vb,
                                               float (*tile)[33]) {
  const int nTK = GK / 32;
  int kt = vb % nTK, nt = vb / nTK;
  int k0 = kt * 32, n0 = nt * 32;
  int rr = threadIdx.x >> 5, cc = threadIdx.x & 31;
#pragma unroll
  for (int p = 0; p < 4; ++p) {
    int kl = p * 8 + rr;
    tile[kl][cc] = src[(size_t)(k0 + kl) * nsrc + n0 + cc];
  }
  __syncthreads();
#pragma unroll
  for (int p = 0; p < 4; ++p) {
    int nl = p * 8 + rr;
    dst[(size_t)(row0 + n0 + nl) * GK + k0 + cc] = f2bf(tile[cc][nl]);
  }
}

__global__ __launch_bounds__(256)
void k_prep(const float* __restrict__ x,  const float* __restrict__ Wq,
            const float* __restrict__ Wk, const float* __restrict__ Wv,
            const float* __restrict__ Wo, u16* __restrict__ xb,
            u16* __restrict__ WqkvT, u16* __restrict__ WoT,
            float2* __restrict__ tab) {
  __shared__ float tile[32][33];
  const int bid = blockIdx.x;
  if (bid < 8192) {                       // fp32 -> bf16 convert, 4 elems/thread
    int i = bid * 256 + threadIdx.x;
    f32x4 v = *(const f32x4*)(x + (size_t)i * 4);
    u16x4 o;
    o[0] = f2bf(v[0]); o[1] = f2bf(v[1]); o[2] = f2bf(v[2]); o[3] = f2bf(v[3]);
    *(u16x4*)(xb + (size_t)i * 4) = o;
  } else if (bid < 12288) {
    prep_transpose(Wq, 2048, WqkvT, 0,    bid - 8192,  tile);
  } else if (bid < 13312) {
    prep_transpose(Wk, 512,  WqkvT, 2048, bid - 12288, tile);
  } else if (bid < 14336) {
    prep_transpose(Wv, 512,  WqkvT, 2560, bid - 13312, tile);
  } else if (bid < 18432) {
    prep_transpose(Wo, 2048, WoT,   0,    bid - 14336, tile);
  } else {                                // rope cos/sin table
    int idx = (bid - 18432) * 256 + threadIdx.x;
    int t = idx >> 5, i = idx & 31;
    float inv = 1.0f / powf(10000.0f, (float)i / 32.0f);
    float ang = (float)t * inv;
    tab[idx] = make_float2(cosf(ang), sinf(ang));
  }
}

// ---------------- bf16 GEMM: C[M][N] = A[M][GK] * Bt[N][GK]^T ----------------
// 128x128 tile, BK=64, 4 waves (2x2), global_load_lds double-buffer,
// T2 XOR swizzle applied via pre-swizzled global source (linear LDS dest).
// T1 XCD-chunked blockIdx swizzle (grids are %8==0 -> bijective): each XCD gets
// a contiguous tm-band so its A-panels stay L2-resident across the tn sweep.
// MODE 0: bf16 out; q|k cols (<2560) get fused RoPE then -> QKV (stride 2560);
//         v cols (>=2560) -> transposed Vt ([b][kvh][d][t]).
// MODE 1: f32 out, stride N.
template <int MODE>
__global__ __launch_bounds__(256, 2)
void k_gemm(const u16* __restrict__ A, const u16* __restrict__ Bt,
            u16* __restrict__ QKV, u16* __restrict__ Vt, float* __restrict__ Cf,
            const float2* __restrict__ tab, int N) {
  __shared__ __align__(16) u16 lds[2][16384];   // per buf: A 128x64 | B 128x64
  const int tid = threadIdx.x;
  const int lane = tid & 63, wid = tid >> 6;
  const int nTN = N >> 7;
  const int cpx = gridDim.x >> 3;               // blocks per XCD chunk
  const int bid = (blockIdx.x & 7) * cpx + (blockIdx.x >> 3);  // T1 chunked swizzle
  const int tm = bid / nTN, tn = bid % nTN;
  const int m0 = tm << 7, n0 = tn << 7;
  const int l15 = lane & 15, lg = lane >> 4;
  const int wr = (wid >> 1) << 6, wc = (wid & 1) << 6;

  f32x4 acc[4][4] = {};

  auto stage = [&](int buf, int k0) {
    u16* base = &lds[buf][0];
#pragma unroll
    for (int p = 0; p < 4; ++p) {
      int c = p * 256 + tid;
      int row = c >> 3, kb = c & 7;
      int ksrc = k0 + ((kb ^ (row & 7)) << 3);   // inverse-swizzled source col
      const u16* sA = A + (size_t)(m0 + row) * GK + ksrc;
      __builtin_amdgcn_global_load_lds((gas_u32*)sA, (las_u32*)(base + c * 8), 16, 0, 0);
      const u16* sB = Bt + (size_t)(n0 + row) * GK + ksrc;
      __builtin_amdgcn_global_load_lds((gas_u32*)sB, (las_u32*)(base + 8192 + c * 8), 16, 0, 0);
    }
  };

  auto compute = [&](int buf) {
    const u16* ldsA = &lds[buf][0];
    const u16* ldsB = &lds[buf][8192];
#pragma unroll
    for (int kk = 0; kk < 2; ++kk) {
      bf16x8 af[4], bfr[4];
#pragma unroll
      for (int m = 0; m < 4; ++m) {
        int row = wr + m * 16 + l15;
        int koff = (kk * 32 + lg * 8) ^ ((row & 7) << 3);
        af[m] = *(const bf16x8*)(ldsA + row * 64 + koff);
      }
#pragma unroll
      for (int n = 0; n < 4; ++n) {
        int row = wc + n * 16 + l15;
        int koff = (kk * 32 + lg * 8) ^ ((row & 7) << 3);
        bfr[n] = *(const bf16x8*)(ldsB + row * 64 + koff);
      }
#pragma unroll
      for (int m = 0; m < 4; ++m)
#pragma unroll
        for (int n = 0; n < 4; ++n)
          acc[m][n] = __builtin_amdgcn_mfma_f32_16x16x32_bf16(af[m], bfr[n], acc[m][n], 0, 0, 0);
    }
  };

  stage(0, 0);
  __syncthreads();
  const int nk = GK / 64;
  for (int t = 0; t < nk; ++t) {
    if (t + 1 < nk) stage((t + 1) & 1, (t + 1) * 64);
    compute(t & 1);
    __syncthreads();
  }

  if (MODE == 1) {
#pragma unroll
    for (int m = 0; m < 4; ++m)
#pragma unroll
      for (int n = 0; n < 4; ++n)
#pragma unroll
        for (int r = 0; r < 4; ++r) {
          int row = m0 + wr + m * 16 + lg * 4 + r;
          int col = n0 + wc + n * 16 + l15;
          Cf[(size_t)row * N + col] = acc[m][n][r];
        }
  } else if (n0 >= 2560) {   // V tile -> transposed Vt[b][kvh][d][t]
#pragma unroll
    for (int m = 0; m < 4; ++m)
#pragma unroll
      for (int n = 0; n < 4; ++n)
#pragma unroll
        for (int r = 0; r < 4; ++r) {
          int row = m0 + wr + m * 16 + lg * 4 + r;
          int col = n0 + wc + n * 16 + l15;
          int dh = col - 2560, kvh = dh >> 6, d = dh & 63;
          int bb = row >> 11, tt = row & 2047;
          Vt[(((size_t)bb * NKV + kvh) * 64 + d) * TQ + tt] = f2bf(acc[m][n][r]);
        }
  } else {                   // q|k tile: fused RoPE (pair partner via shfl_xor 1)
#pragma unroll
    for (int m = 0; m < 4; ++m)
#pragma unroll
      for (int n = 0; n < 4; ++n) {
        int col = n0 + wc + n * 16 + l15;
        int dh = (col & 63) >> 1;
        float sgn = (col & 1) ? 1.0f : -1.0f;
#pragma unroll
        for (int r = 0; r < 4; ++r) {
          int row = m0 + wr + m * 16 + lg * 4 + r;
          float a = acc[m][n][r];
          float b = __shfl_xor(a, 1);
          int t = row & (TQ - 1);
          float2 csv = tab[t * 32 + dh];
          float o = a * csv.x + sgn * b * csv.y;
          QKV[(size_t)row * QK_W + col] = f2bf(o);
        }
      }
  }
}

// ---------------- causal GQA flash attention (round-4 proven version) ----------------
// block = (b,h,q-tile of 128). 4 waves x 32 q rows. KVBLK=64.
// Swapped orientation: S^T = mfma(K,Q), lane owns full softmax rows (q=l15);
// O^T = mfma(V^T,P). Double-buffered global_load_lds staging, one barrier/tile.
// Raw-score softmax with exp2 folding; defer-max (raw thr 64 = e^8); cvtpk P-store.
// No XCD swizzle here: it would break the heavy-first LPT balance (r12 lesson:
// grid depth + inter-block overlap dominate for causal attention).
__global__ __launch_bounds__(256, 3)
void k_attn(const u16* __restrict__ QKV, const u16* __restrict__ Vt, u16* __restrict__ ctx) {
  __shared__ __align__(16) u16 Ksh[2][4096];   // [kv 64][d 64] col-swizzled
  __shared__ __align__(16) u16 Vsh[2][4096];   // [d 64][t 64] col-swizzled
  __shared__ __align__(16) u16 Psh[4][2048];   // per-wave [32 q][64 kv] swizzled
  const int tid = threadIdx.x, lane = tid & 63, w = tid >> 6;
  const int l15 = lane & 15, lg = lane >> 4;
  const int bid = blockIdx.x;
  const int qt = 15 - (bid >> 6);              // heavy-first
  const int hb = bid & 63;
  const int h = hb & 31, b = hb >> 5;
  const int kvh = h >> 2;                      // G=4
  const int q0 = qt << 7;
  const int qb = q0 + w * 32;                  // this wave's first q row
  const size_t rowbase = (size_t)b * TQ;
  const u16* Vg = Vt + ((size_t)(b * NKV + kvh)) * 64 * TQ;

  auto stage = [&](int buf, int kv0) {
    u16* kd = &Ksh[buf][0];
    u16* vd = &Vsh[buf][0];
#pragma unroll
    for (int p = 0; p < 2; ++p) {
      int c = p * 256 + tid;
      int row = c >> 3, kb = c & 7;
      int off = (kb ^ (row & 7)) << 3;
      const u16* sK = QKV + (rowbase + kv0 + row) * QK_W + 2048 + kvh * 64 + off;
      __builtin_amdgcn_global_load_lds((gas_u32*)sK, (las_u32*)(kd + c * 8), 16, 0, 0);
      const u16* sV = Vg + (size_t)row * TQ + kv0 + off;
      __builtin_amdgcn_global_load_lds((gas_u32*)sV, (las_u32*)(vd + c * 8), 16, 0, 0);
    }
  };

  bf16x8 qf[2][2];
#pragma unroll
  for (int m = 0; m < 2; ++m)
#pragma unroll
    for (int kk = 0; kk < 2; ++kk)
      qf[m][kk] = *(const bf16x8*)(QKV + (rowbase + qb + m * 16 + l15) * QK_W + h * 64 + kk * 32 + lg * 8);

  float m_run[2] = {NEG, NEG}, l_run[2] = {0.f, 0.f};
  f32x4 oacc[2][4] = {};

  stage(0, 0);
  const int nt = 2 * qt + 2;
  for (int t = 0; t < nt; ++t) {
    const int kv0 = t << 6;
    __syncthreads();                  // drains vmcnt(0): buf[t&1] ready block-wide
    if (t + 1 < nt) stage((t + 1) & 1, kv0 + 64);
    if (kv0 > qb + 31) continue;      // this wave fully above diagonal for this tile

    const u16* Kl = &Ksh[t & 1][0];
    const u16* Vl = &Vsh[t & 1][0];

    // S^T = K * Q (raw scores): lane owns col q = qb+m*16+l15, row kv = kv0+c*16+lg*4+r
    f32x4 stv[2][4];
#pragma unroll
    for (int c = 0; c < 4; ++c) {
      const int krow = c * 16 + l15;
      const int ks = (krow & 7) << 3;
      f32x4 z0 = {}, z1 = {};
#pragma unroll
      for (int kk = 0; kk < 2; ++kk) {
        bf16x8 kf = *(const bf16x8*)(Kl + krow * 64 + ((kk * 32 + lg * 8) ^ ks));
        z0 = __builtin_amdgcn_mfma_f32_16x16x32_bf16(kf, qf[0][kk], z0, 0, 0, 0);
        z1 = __builtin_amdgcn_mfma_f32_16x16x32_bf16(kf, qf[1][kk], z1, 0, 0, 0);
      }
      stv[0][c] = z0; stv[1][c] = z1;
    }

    const bool maskT = (kv0 + 63 > qb);
    float mt[2];
    if (maskT) {
#pragma unroll
      for (int m = 0; m < 2; ++m) {
        const int qpos = qb + m * 16 + l15;
        float mx = NEG;
#pragma unroll
        for (int c = 0; c < 4; ++c)
#pragma unroll
          for (int r = 0; r < 4; ++r) {
            int kvpos = kv0 + c * 16 + lg * 4 + r;
            float sv = stv[m][c][r];
            sv = (kvpos > qpos) ? NEG : sv;
            stv[m][c][r] = sv;
            mx = fmaxf(mx, sv);
          }
        mt[m] = mx;
      }
    } else {
#pragma unroll
      for (int m = 0; m < 2; ++m) {
        float mx = NEG;
#pragma unroll
        for (int c = 0; c < 4; ++c)
#pragma unroll
          for (int r = 0; r < 4; ++r) mx = fmaxf(mx, stv[m][c][r]);
        mt[m] = mx;
      }
    }
#pragma unroll
    for (int m = 0; m < 2; ++m) {
      mt[m] = fmaxf(mt[m], __shfl_xor(mt[m], 16));
      mt[m] = fmaxf(mt[m], __shfl_xor(mt[m], 32));
    }

    // defer-max: rescale only when some row grew past raw-threshold 64 (= e^8)
    if (__any((mt[0] > m_run[0] + 64.0f) || (mt[1] > m_run[1] + 64.0f))) {
#pragma unroll
      for (int m = 0; m < 2; ++m) {
        float nm = fmaxf(m_run[m], mt[m]);
        float sc = exp2g((m_run[m] - nm) * CL2);
        m_run[m] = nm;
        l_run[m] *= sc;
#pragma unroll
        for (int dt = 0; dt < 4; ++dt) oacc[m][dt] *= sc;
      }
    }

    // P = exp2(S*CL2 - m*CL2) -> bf16 per-wave LDS [q][kv] (swizzled), row-sum
    u16* Pw = &Psh[w][0];
#pragma unroll
    for (int m = 0; m < 2; ++m) {
      const float msc = m_run[m] * CL2;
      float ssum = 0.f;
      const int rowp = m * 16 + l15;
      const int swz = (l15 & 7) << 3;
#pragma unroll
      for (int c = 0; c < 4; ++c) {
        float p0 = exp2g(stv[m][c][0] * CL2 - msc);
        float p1 = exp2g(stv[m][c][1] * CL2 - msc);
        float p2 = exp2g(stv[m][c][2] * CL2 - msc);
        float p3 = exp2g(stv[m][c][3] * CL2 - msc);
        ssum += (p0 + p1) + (p2 + p3);
        const int kvb = (c * 16 + lg * 4) ^ swz;
        *(u32*)(Pw + rowp * 64 + kvb)       = cvtpk(p0, p1);
        *(u32*)(Pw + rowp * 64 + (kvb | 2)) = cvtpk(p2, p3);
      }
      ssum += __shfl_xor(ssum, 16);
      ssum += __shfl_xor(ssum, 32);
      l_run[m] += ssum;
    }

    // O^T += V^T * P : lane owns O^T[d = dt*16+lg*4+r][q = l15]
    bf16x8 pf[2][2];
#pragma unroll
    for (int m = 0; m < 2; ++m)
#pragma unroll
      for (int kc = 0; kc < 2; ++kc)
        pf[m][kc] = *(const bf16x8*)(Pw + (m * 16 + l15) * 64 + ((kc * 32 + lg * 8) ^ ((l15 & 7) << 3)));
#pragma unroll
    for (int dt = 0; dt < 4; ++dt) {
      const int vrow = dt * 16 + l15;
      const int vs = (vrow & 7) << 3;
#pragma unroll
      for (int kc = 0; kc < 2; ++kc) {
        bf16x8 vf = *(const bf16x8*)(Vl + vrow * 64 + ((kc * 32 + lg * 8) ^ vs));
        oacc[0][dt] = __builtin_amdgcn_mfma_f32_16x16x32_bf16(vf, pf[0][kc], oacc[0][dt], 0, 0, 0);
        oacc[1][dt] = __builtin_amdgcn_mfma_f32_16x16x32_bf16(vf, pf[1][kc], oacc[1][dt], 0, 0, 0);
      }
    }
  }

  // epilogue: normalize, write ctx[q][h*64+d] as u32 pairs
#pragma unroll
  for (int m = 0; m < 2; ++m) {
    float inv = 1.0f / l_run[m];
    size_t row = rowbase + qb + m * 16 + l15;
#pragma unroll
    for (int dt = 0; dt < 4; ++dt) {
      int col = h * 64 + dt * 16 + lg * 4;
      u32 w0 = cvtpk(oacc[m][dt][0] * inv, oacc[m][dt][1] * inv);
      u32 w1 = cvtpk(oacc[m][dt][2] * inv, oacc[m][dt][3] * inv);
      *(u32*)(ctx + row * DOUT + col) = w0;
      *(u32*)(ctx + row * DOUT + col + 2) = w1;
    }
  }
}

// ---------------- host launcher ----------------
extern "C" void kernel_launch(void* const* d_in, const int* in_sizes, int n_in,
                              void* d_out, int out_size, void* d_ws, size_t ws_size,
                              hipStream_t stream) {
  const float* x  = (const float*)d_in[0];
  const float* Wq = (const float*)d_in[1];
  const float* Wk = (const float*)d_in[2];
  const float* Wv = (const float*)d_in[3];
  const float* Wo = (const float*)d_in[4];
  float* out = (float*)d_out;

  char* ws = (char*)d_ws;
  size_t off = 0;
  auto alloc = [&](size_t bytes) -> void* {
    void* p = ws + off;
    off += (bytes + 255) & ~(size_t)255;
    return p;
  };
  const int rows = NB * TQ;  // 4096
  u16*    xb    = (u16*)alloc((size_t)rows * DIN * 2);
  u16*    WqkvT = (u16*)alloc((size_t)NQKV * GK * 2);
  u16*    WoT   = (u16*)alloc((size_t)DOUT * GK * 2);
  u16*    QKV   = (u16*)alloc((size_t)rows * QK_W * 2);
  u16*    Vt    = (u16*)alloc((size_t)NB * NKV * 64 * TQ * 2);
  u16*    ctx   = (u16*)alloc((size_t)rows * DOUT * 2);
  float2* tab   = (float2*)alloc((size_t)TQ * 32 * sizeof(float2));

  k_prep<<<dim3(18688), dim3(256), 0, stream>>>(x, Wq, Wk, Wv, Wo, xb, WqkvT, WoT, tab);
  k_gemm<0><<<dim3((rows / 128) * (NQKV / 128)), dim3(256), 0, stream>>>(xb, WqkvT, QKV, Vt, nullptr, tab, NQKV);
  k_attn<<<dim3(NB * NH * (TQ / 128)), dim3(256), 0, stream>>>(QKV, Vt, ctx);
  k_gemm<1><<<dim3((rows / 128) * (DOUT / 128)), dim3(256), 0, stream>>>(ctx, WoT, nullptr, nullptr, out, nullptr, DOUT);
}